// Round 12
// baseline (446.496 us; speedup 1.0000x reference)
//
#include <hip/hip_runtime.h>
#include <stdint.h>
#include <stddef.h>

// CapsuleFC: B=64, N_IN=2048, D_IN=16, N_OUT=64, D_OUT=16
constexpr int B_ = 64, N_ = 2048, A_ = 16, M_ = 64, D_ = 16;
constexpr float SCALE_ = 0.25f;   // 1/sqrt(16)
constexpr float EPS_ = 1e-6f;

typedef float f32x4 __attribute__((ext_vector_type(4)));

#define GL16(g, l)                                                             \
  __builtin_amdgcn_global_load_lds((__attribute__((address_space(1))) void*)(g), \
                                   (__attribute__((address_space(3))) void*)(l), \
                                   16, 0, 0)

// ---- explicit AGPR residency (gfx950 unified VGPR/AGPR file, ISA §10).
// Session evidence (R3-R11): per-thread live set is structurally 192 floats
// (v64+acc64+cv64) vs the 128-VGPR class -> every schedule variant spilled
// (cv reloaded from L2 scratch per n at best, 0.5GB/kernel; catastrophic at
// worst). At VGPR=128 the HW granule is 256 regs/wave (occupancy pinned at
// 8 waves/CU) -> 128 AGPRs are allocated but IDLE. Park acc+cv there.
__device__ __forceinline__ float ar(const float& a) {
  float r;
  asm volatile("v_accvgpr_read_b32 %0, %1" : "=v"(r) : "a"(a));
  return r;
}
__device__ __forceinline__ void aw(float& a, float x) {
  asm volatile("v_accvgpr_write_b32 %0, %1" : "=a"(a) : "v"(x));
}

// grid: 4*nch blocks (nch=256 -> 1024). block: 256 threads = 4 waves;
// wave wv owns 4 batches (b0 = bg*16 + wv*4); lane l owns out-capsule m=l.
// Structure = R8 verbatim (best measured: 177us, FETCH 77MB, WRITE 133MB):
// single 32KB a-half buffer, plain __syncthreads, s_load inputs.
// Only delta: acc[4][16] and cv[4][16] live in AGPRs.
__global__ __launch_bounds__(256, 2)
void caps_main(
    const float* __restrict__ input,   // [B,N,A]
    const float* __restrict__ cact,    // [B,N]
    const float* __restrict__ ncv,     // [B,M,D]
    const float* __restrict__ nact,    // [B,M]
    const float* __restrict__ w,       // [N,A,M,D]
    float* __restrict__ qk_out,        // [B,N,M]
    float* __restrict__ partial,       // [nch,B,M,D]
    int C, int nch)
{
  __shared__ __align__(128) char wl[32768];   // one 32KB a-half slab (swizzled)

  const int tid  = threadIdx.x;
  const int lane = tid & 63;
  const int wv   = __builtin_amdgcn_readfirstlane(tid >> 6);

  // co-XCD mapping: the 4 bgroup-sharers of chunk ch land on xcd = flat&7
  const int flat = blockIdx.x;
  int bg, ch;
  if (nch & 7) { bg = flat & 3; ch = flat >> 2; }
  else { bg = (flat >> 3) & 3; ch = ((flat >> 5) << 3) | (flat & 7); }

  const int b0 = bg * 16 + wv * 4;
  const int n0 = ch * C;

  // swizzled LDS read offsets (pairs with the stage-side source involution:
  // bits[6:4] ^= bits[9:7])
  int offj[4];
#pragma unroll
  for (int j = 0; j < 4; ++j)
    offj[j] = (lane * 64 + j * 16) ^ (((lane >> 1) & 7) << 4);

  // loop-invariant per-(b,m): next_act in VGPR (4), ncv -> AGPRs (64)
  float na[4];
  float cva[4][16];   // AGPR-resident (via aw/ar)
#pragma unroll
  for (int bi = 0; bi < 4; ++bi) {
    na[bi] = nact[(b0 + bi) * M_ + lane];
    const f32x4* np4 = (const f32x4*)(ncv + ((size_t)(b0 + bi) * M_ + lane) * D_);
#pragma unroll
    for (int j = 0; j < 4; ++j) {
      const f32x4 t = np4[j];
      aw(cva[bi][4*j+0], t.x); aw(cva[bi][4*j+1], t.y);
      aw(cva[bi][4*j+2], t.z); aw(cva[bi][4*j+3], t.w);
    }
  }

  float acca[4][16];  // AGPR-resident accumulator
#pragma unroll
  for (int bi = 0; bi < 4; ++bi)
#pragma unroll
    for (int d = 0; d < 16; ++d) aw(acca[bi][d], 0.f);

  for (int k = 0; k < C; ++k) {
    const int n = n0 + k;

    float v[4][16];
#pragma unroll
    for (int bi = 0; bi < 4; ++bi)
#pragma unroll
      for (int d = 0; d < 16; ++d) v[bi][d] = 0.f;

    int ibase[4];
#pragma unroll
    for (int bi = 0; bi < 4; ++bi)
      ibase[bi] = __builtin_amdgcn_readfirstlane(((b0 + bi) * N_ + n) * A_);

    // ---- two a-halves through the same 32KB buffer
#pragma unroll
    for (int h = 0; h < 2; ++h) {
      {  // stage a-half h of w[n]: source pre-swizzled, LDS dest linear
        const char* ws = (const char*)w + ((size_t)n << 16) + ((size_t)h << 15);
#pragma unroll
        for (int i = 0; i < 8; ++i) {
          const uint32_t P = (uint32_t)(i * 4096 + tid * 16);
          const uint32_t S = P ^ (((P >> 7) & 7u) << 4);
          GL16(ws + S, (char*)wl + i * 4096 + wv * 1024);
        }
      }
      __syncthreads();   // slab half ready (drains vmcnt)

#pragma unroll
      for (int al = 0; al < 8; ++al) {
        f32x4 wr[4];
#pragma unroll
        for (int j = 0; j < 4; ++j)
          wr[j] = *(const f32x4*)((const char*)wl + al * 4096 + offj[j]);
#pragma unroll
        for (int bi = 0; bi < 4; ++bi) {
          const float x = input[ibase[bi] + h * 8 + al];  // wave-uniform s_load
#pragma unroll
          for (int j = 0; j < 4; ++j) {
            v[bi][4*j+0] += x * wr[j].x; v[bi][4*j+1] += x * wr[j].y;
            v[bi][4*j+2] += x * wr[j].z; v[bi][4*j+3] += x * wr[j].w;
          }
        }
      }
      __syncthreads();   // all waves done reading before restage
    }

    // ---- scores -> wave-local softmax (m = lane) -> qk -> accumulate
#pragma unroll
    for (int bi = 0; bi < 4; ++bi) {
      float s = 0.f;
#pragma unroll
      for (int d = 0; d < 16; ++d) s += v[bi][d] * ar(cva[bi][d]);
      s *= SCALE_;
      // |s| small (~N(0,0.2)); max-subtraction cancels in the ratio -> skip
      const float e = __expf(s);
      const float ena = e * na[bi];
      float Ps = ena;
#pragma unroll
      for (int off = 32; off >= 1; off >>= 1) Ps += __shfl_xor(Ps, off, 64);
      const float qk = ena / Ps;   // 1e-10 terms ~2e-10 relative: dropped
      qk_out[((size_t)(b0 + bi) * N_ + n) * M_ + lane] = qk;
      float ab = cact[__builtin_amdgcn_readfirstlane((b0 + bi) * N_ + n)];
      ab = fminf(fmaxf(ab, EPS_), 1.0f - EPS_);
      const float wq = qk * ab;
#pragma unroll
      for (int d = 0; d < 16; ++d)
        aw(acca[bi][d], fmaf(wq, v[bi][d], ar(acca[bi][d])));
    }
  }

  // partial[ch][b][m][d]
#pragma unroll
  for (int bi = 0; bi < 4; ++bi) {
    float* pp = partial + (((size_t)ch * B_ + (b0 + bi)) * M_ + lane) * D_;
#pragma unroll
    for (int j = 0; j < 4; ++j) {
      f32x4 t;
      t.x = ar(acca[bi][4*j+0]); t.y = ar(acca[bi][4*j+1]);
      t.z = ar(acca[bi][4*j+2]); t.w = ar(acca[bi][4*j+3]);
      __builtin_nontemporal_store(t, (f32x4*)pp + j);
    }
  }
}

__global__ void caps_reduce(const float* __restrict__ part,
                            const float* __restrict__ nain,
                            float* __restrict__ out, int nch)
{
  const int i = blockIdx.x * 256 + threadIdx.x;  // one thread per out[b,m,d]
  float s = 0.f;
  for (int c = 0; c < nch; ++c) s += part[(size_t)c * (B_ * M_ * D_) + i];
  out[i] = s;
  if (i < B_ * M_) out[B_ * M_ * D_ + i] = nain[i];  // next_act passthrough
}

extern "C" void kernel_launch(void* const* d_in, const int* in_sizes, int n_in,
                              void* d_out, int out_size, void* d_ws, size_t ws_size,
                              hipStream_t stream)
{
  const float* input = (const float*)d_in[0];
  const float* cact  = (const float*)d_in[1];
  const float* ncv   = (const float*)d_in[2];
  const float* nact  = (const float*)d_in[3];
  const float* w     = (const float*)d_in[4];

  float* out     = (float*)d_out;
  float* qk_out  = out + (B_ * M_ * D_) + (B_ * M_);   // after out and next_act
  float* partial = (float*)d_ws;

  // nch=256 -> grid 1024; needs 67MB ws; degrade if smaller
  int nch = 256;
  while ((size_t)nch * (size_t)(B_ * M_ * D_) * sizeof(float) > ws_size && nch > 32) nch >>= 1;
  const int C = N_ / nch;

  hipLaunchKernelGGL(caps_main, dim3(4 * nch), dim3(256), 0, stream,
                     input, cact, ncv, nact, w, qk_out, partial, C, nch);
  hipLaunchKernelGGL(caps_reduce, dim3(B_ * M_ * D_ / 256), dim3(256), 0, stream,
                     partial, nact, out, nch);
}

// Round 13
// 223.861 us; speedup vs baseline: 1.9945x; 1.9945x over previous
//
#include <hip/hip_runtime.h>
#include <stdint.h>
#include <stddef.h>

// CapsuleFC: B=64, N_IN=2048, D_IN=16, N_OUT=64, D_OUT=16
constexpr int B_ = 64, N_ = 2048, A_ = 16, M_ = 64, D_ = 16;
constexpr float SCALE_ = 0.25f;   // 1/sqrt(16)
constexpr float EPS_ = 1e-6f;

typedef float f32x4 __attribute__((ext_vector_type(4)));

#define GL16(g, l)                                                             \
  __builtin_amdgcn_global_load_lds((__attribute__((address_space(1))) void*)(g), \
                                   (__attribute__((address_space(3))) void*)(l), \
                                   16, 0, 0)

__device__ __forceinline__ float rdlane(float v, int l) {
  return __uint_as_float(__builtin_amdgcn_readlane(__float_as_uint(v), l));
}

// grid: 4*nch blocks (nch=256 -> 1024). block: 256 threads = 4 waves;
// wave wv owns 4 batches (b0 = bg*16 + wv*4); lane l owns out-capsule m=l.
//
// Structure = R8 verbatim (best: 177us; regalloc sweet spot — LLVM parks the
// accumulator in AGPRs itself: VGPR=128 + ~128 AGPR -> 8 waves/CU).
// R13 single delta: R8 issued 32 wave-uniform s_load input reads + 4 cact
// reads per n INSIDE the FMA loop -> scalar-cache demand misses were the
// dominant stall (VALUBusy 23% of 177us). Inputs are 64 floats/wave/n = ONE
// per-lane VGPR: prefetch next-n into inext/canext at loop top (drains free
// under the existing stage barrier), broadcast via v_readlane (const lane).
__global__ __launch_bounds__(256, 2)
void caps_main(
    const float* __restrict__ input,   // [B,N,A]
    const float* __restrict__ cact,    // [B,N]
    const float* __restrict__ ncv,     // [B,M,D]
    const float* __restrict__ nact,    // [B,M]
    const float* __restrict__ w,       // [N,A,M,D]
    float* __restrict__ qk_out,        // [B,N,M]
    float* __restrict__ partial,       // [nch,B,M,D]
    int C, int nch)
{
  __shared__ __align__(128) char wl[32768];   // one 32KB a-half slab (swizzled)

  const int tid  = threadIdx.x;
  const int lane = tid & 63;
  const int wv   = __builtin_amdgcn_readfirstlane(tid >> 6);

  // co-XCD mapping: the 4 bgroup-sharers of chunk ch land on xcd = flat&7
  const int flat = blockIdx.x;
  int bg, ch;
  if (nch & 7) { bg = flat & 3; ch = flat >> 2; }
  else { bg = (flat >> 3) & 3; ch = ((flat >> 5) << 3) | (flat & 7); }

  const int b0 = bg * 16 + wv * 4;
  const int n0 = ch * C;

  // swizzled LDS read offsets (pairs with the stage-side source involution:
  // bits[6:4] ^= bits[9:7])
  int offj[4];
#pragma unroll
  for (int j = 0; j < 4; ++j)
    offj[j] = (lane * 64 + j * 16) ^ (((lane >> 1) & 7) << 4);

  // per-lane input/cact carriers:
  //   icur: lane l holds input[b0 + (l>>4)][n][l&15]
  //   cacur: lane l holds cact[b0 + (l&3)][n]
  const int ib_row = b0 + (lane >> 4);
  const int ia_col = lane & 15;
  const int cb_row = b0 + (lane & 3);

  // loop-invariant per-(b,m) values in registers
  float na[4], cv[4][16];
#pragma unroll
  for (int bi = 0; bi < 4; ++bi) {
    na[bi] = nact[(b0 + bi) * M_ + lane];
    const f32x4* np4 = (const f32x4*)(ncv + ((size_t)(b0 + bi) * M_ + lane) * D_);
#pragma unroll
    for (int j = 0; j < 4; ++j) {
      const f32x4 t = np4[j];
      cv[bi][4*j+0] = t.x; cv[bi][4*j+1] = t.y;
      cv[bi][4*j+2] = t.z; cv[bi][4*j+3] = t.w;
    }
  }

  float acc[4][16];
#pragma unroll
  for (int bi = 0; bi < 4; ++bi)
#pragma unroll
    for (int d = 0; d < 16; ++d) acc[bi][d] = 0.f;

  // prologue prefetch for n0 (drained by the first in-loop barrier)
  float icur  = input[(size_t)(ib_row * N_ + n0) * A_ + ia_col];
  float cacur = cact[(size_t)cb_row * N_ + n0];

  for (int k = 0; k < C; ++k) {
    const int n  = n0 + k;
    const int nn = (k + 1 < C) ? (n + 1) : n;   // OOB guard on last iter

    // prefetch next-n input/cact (2 vmem loads; drain under stage barrier)
    float inext  = input[(size_t)(ib_row * N_ + nn) * A_ + ia_col];
    float canext = cact[(size_t)cb_row * N_ + nn];

    float v[4][16];
#pragma unroll
    for (int bi = 0; bi < 4; ++bi)
#pragma unroll
      for (int d = 0; d < 16; ++d) v[bi][d] = 0.f;

    // ---- two a-halves through the same 32KB buffer
#pragma unroll
    for (int h = 0; h < 2; ++h) {
      {  // stage a-half h of w[n]: source pre-swizzled, LDS dest linear
        const char* ws = (const char*)w + ((size_t)n << 16) + ((size_t)h << 15);
#pragma unroll
        for (int i = 0; i < 8; ++i) {
          const uint32_t P = (uint32_t)(i * 4096 + tid * 16);
          const uint32_t S = P ^ (((P >> 7) & 7u) << 4);
          GL16(ws + S, (char*)wl + i * 4096 + wv * 1024);
        }
      }
      __syncthreads();   // slab half ready (drains vmcnt, incl. prefetches)

#pragma unroll
      for (int al = 0; al < 8; ++al) {
        f32x4 wr[4];
#pragma unroll
        for (int j = 0; j < 4; ++j)
          wr[j] = *(const f32x4*)((const char*)wl + al * 4096 + offj[j]);
#pragma unroll
        for (int bi = 0; bi < 4; ++bi) {
          // broadcast input[b0+bi][n][h*8+al] from lane (bi*16 + h*8 + al)
          const float x = rdlane(icur, bi * 16 + h * 8 + al);
#pragma unroll
          for (int j = 0; j < 4; ++j) {
            v[bi][4*j+0] += x * wr[j].x; v[bi][4*j+1] += x * wr[j].y;
            v[bi][4*j+2] += x * wr[j].z; v[bi][4*j+3] += x * wr[j].w;
          }
        }
      }
      __syncthreads();   // all waves done reading before restage
    }

    // ---- scores -> wave-local softmax (m = lane) -> qk -> accumulate
#pragma unroll
    for (int bi = 0; bi < 4; ++bi) {
      float s = 0.f;
#pragma unroll
      for (int d = 0; d < 16; ++d) s += v[bi][d] * cv[bi][d];
      s *= SCALE_;
      // |s| small (~N(0,0.2)); max-subtraction cancels in the ratio -> skip
      const float e = __expf(s);
      const float ena = e * na[bi];
      float Ps = ena;
#pragma unroll
      for (int off = 32; off >= 1; off >>= 1) Ps += __shfl_xor(Ps, off, 64);
      const float qk = ena / Ps;   // 1e-10 terms ~2e-10 relative: dropped
      qk_out[((size_t)(b0 + bi) * N_ + n) * M_ + lane] = qk;
      float ab = rdlane(cacur, bi);
      ab = fminf(fmaxf(ab, EPS_), 1.0f - EPS_);
      const float wq = qk * ab;
#pragma unroll
      for (int d = 0; d < 16; ++d) acc[bi][d] += wq * v[bi][d];
    }

    icur  = inext;
    cacur = canext;
  }

  // partial[ch][b][m][d]
#pragma unroll
  for (int bi = 0; bi < 4; ++bi) {
    float* pp = partial + (((size_t)ch * B_ + (b0 + bi)) * M_ + lane) * D_;
#pragma unroll
    for (int j = 0; j < 4; ++j) {
      f32x4 t;
      t.x = acc[bi][4*j+0]; t.y = acc[bi][4*j+1];
      t.z = acc[bi][4*j+2]; t.w = acc[bi][4*j+3];
      __builtin_nontemporal_store(t, (f32x4*)pp + j);
    }
  }
}

__global__ void caps_reduce(const float* __restrict__ part,
                            const float* __restrict__ nain,
                            float* __restrict__ out, int nch)
{
  const int i = blockIdx.x * 256 + threadIdx.x;  // one thread per out[b,m,d]
  float s = 0.f;
  for (int c = 0; c < nch; ++c) s += part[(size_t)c * (B_ * M_ * D_) + i];
  out[i] = s;
  if (i < B_ * M_) out[B_ * M_ * D_ + i] = nain[i];  // next_act passthrough
}

extern "C" void kernel_launch(void* const* d_in, const int* in_sizes, int n_in,
                              void* d_out, int out_size, void* d_ws, size_t ws_size,
                              hipStream_t stream)
{
  const float* input = (const float*)d_in[0];
  const float* cact  = (const float*)d_in[1];
  const float* ncv   = (const float*)d_in[2];
  const float* nact  = (const float*)d_in[3];
  const float* w     = (const float*)d_in[4];

  float* out     = (float*)d_out;
  float* qk_out  = out + (B_ * M_ * D_) + (B_ * M_);   // after out and next_act
  float* partial = (float*)d_ws;

  // nch=256 -> grid 1024; needs 67MB ws; degrade if smaller
  int nch = 256;
  while ((size_t)nch * (size_t)(B_ * M_ * D_) * sizeof(float) > ws_size && nch > 32) nch >>= 1;
  const int C = N_ / nch;

  hipLaunchKernelGGL(caps_main, dim3(4 * nch), dim3(256), 0, stream,
                     input, cact, ncv, nact, w, qk_out, partial, C, nch);
  hipLaunchKernelGGL(caps_reduce, dim3(B_ * M_ * D_ / 256), dim3(256), 0, stream,
                     partial, nact, out, nch);
}